// Round 8
// baseline (374.620 us; speedup 1.0000x reference)
//
#include <hip/hip_runtime.h>
#include <stdint.h>
#include <math.h>

// MixtureOfDepths: B=4, L=4096, D=1024, Dff=4096, capacity 0.5 -> k=2048.
// R12 -> R13: REVERT R12's 3-barrier window (regressed 109->137.5us: extra
// lockstep barriers at 1 block/CU cost ~420cy each; operands still weren't
// ready at cluster start). Restore R10 single-barrier ring and add the
// missing piece: depth-1 REGISTER pipeline on fragments (m201's actual
// mechanism). Window t: stage slot t+3 (ring distance 3; slots t..t+3 =
// ag-read/next-read/landed/landing -- exactly 4); issue ag(t) + af/bfr(t+1)
// ds_reads; sched_barrier(0); MFMA clusters on af/bfr(t) ALREADY IN REGS
// (matrix pipe starts at barrier-open; LDS services the new reads under the
// 1241cy MFMA block); vmcnt(4|3) counted (retires stage(t+2); never 0 in
// steady state); s_barrier. Hazards: reads of slot t+1 need stage(t+1)
// retired -- guaranteed by vmcnt(LW) at end of window t-1 (newest LW
// outstanding = stage(t+2)); slot overwrite at window s-3 is >=2 barriers
// after slot s's last readers. Even-NT unroll-2 with named E/O register
// sets (static indexing, rule #20). Per-element MFMA k-order unchanged ->
// absmax identical.

typedef __attribute__((ext_vector_type(8))) __bf16 bf16x8;
typedef __attribute__((ext_vector_type(4))) float f32x4;

__device__ __forceinline__ void async_cp16(const __bf16* g, __bf16* l) {
    __builtin_amdgcn_global_load_lds(
        (__attribute__((address_space(1))) void*)g,
        (__attribute__((address_space(3))) void*)l,
        16, 0, 0);
}

// gelu_tanh(x) == x * sigmoid(2*0.7978845608*(x + 0.044715 x^3)), exactly.
__device__ __forceinline__ float gelu_fast(float x) {
    float u = 1.5957691216057308f * x * (1.0f + 0.044715f * x * x);
    return x / (1.0f + __expf(-u));
}

// ---------- merged: router scores + x->bf16 (blocks < NBR) and
//            weights->bf16 (blocks >= NBR) ----------
// NOTE: score math must stay bit-identical across rounds (selection boundary).
__global__ __launch_bounds__(256) void prep(
    const float* __restrict__ x, const float* __restrict__ wr,
    float* __restrict__ scores, __bf16* __restrict__ xb,
    const float* __restrict__ p0, const float* __restrict__ p1,
    const float* __restrict__ p2,
    __bf16* __restrict__ o0, __bf16* __restrict__ o1, __bf16* __restrict__ o2,
    int nbr, int c0, int c1, int c2)
{
    if ((int)blockIdx.x < nbr) {
        int wid  = (blockIdx.x * blockDim.x + threadIdx.x) >> 6;  // token id
        int lane = threadIdx.x & 63;
        const float* row = x + (size_t)wid * 1024;
        __bf16* orow = xb + (size_t)wid * 1024;
        double s = 0.0;
        #pragma unroll
        for (int it = 0; it < 2; ++it) {
            int base = it * 512 + lane * 8;
            float4 a  = *(const float4*)(row + base);
            float4 b  = *(const float4*)(row + base + 4);
            float4 wa = *(const float4*)(wr + base);
            float4 wc = *(const float4*)(wr + base + 4);
            s += (double)a.x * wa.x + (double)a.y * wa.y
               + (double)a.z * wa.z + (double)a.w * wa.w
               + (double)b.x * wc.x + (double)b.y * wc.y
               + (double)b.z * wc.z + (double)b.w * wc.w;
            bf16x8 v;
            v[0] = (__bf16)a.x; v[1] = (__bf16)a.y; v[2] = (__bf16)a.z; v[3] = (__bf16)a.w;
            v[4] = (__bf16)b.x; v[5] = (__bf16)b.y; v[6] = (__bf16)b.z; v[7] = (__bf16)b.w;
            *(bf16x8*)(orow + base) = v;
        }
        #pragma unroll
        for (int off = 32; off > 0; off >>= 1) s += __shfl_down(s, off, 64);
        if (lane == 0) scores[wid] = (float)s;
        return;
    }
    int chunk = (blockIdx.x - nbr) * 256 + threadIdx.x;
    const float* in; __bf16* out;
    if (chunk < c0)                { in = p0 + (size_t)chunk * 8;             out = o0 + (size_t)chunk * 8; }
    else if (chunk < c0 + c1)      { int c = chunk - c0;      in = p1 + (size_t)c * 8; out = o1 + (size_t)c * 8; }
    else if (chunk < c0 + c1 + c2) { int c = chunk - c0 - c1; in = p2 + (size_t)c * 8; out = o2 + (size_t)c * 8; }
    else return;
    float4 a = *(const float4*)(in);
    float4 b = *(const float4*)(in + 4);
    bf16x8 v;
    v[0] = (__bf16)a.x; v[1] = (__bf16)a.y; v[2] = (__bf16)a.z; v[3] = (__bf16)a.w;
    v[4] = (__bf16)b.x; v[5] = (__bf16)b.y; v[6] = (__bf16)b.z; v[7] = (__bf16)b.w;
    *(bf16x8*)(out) = v;
}

// ---------------- per-batch top-k via 8-bit MSB-first radix select ----------------
// Same selected set as a full descending sort with tie-break "lower index wins".
__global__ __launch_bounds__(1024) void topk_build(
    const float* __restrict__ scores,
    int* __restrict__ sel_rows, int* __restrict__ byp_rows)
{
    const int L = 4096, K = 2048;
    __shared__ unsigned u[4096];
    __shared__ int hist[256];
    __shared__ int scan_s[1024];
    __shared__ unsigned s_pref;
    __shared__ int s_kk;
    int b = blockIdx.x, t = threadIdx.x;

    for (int i = t; i < L; i += 1024) {
        unsigned v = __float_as_uint(scores[b * L + i]);
        v = (v & 0x80000000u) ? ~v : (v | 0x80000000u);   // order-preserving map
        u[i] = v;
    }
    if (t == 0) { s_pref = 0; s_kk = K; }
    __syncthreads();

    for (int shift = 24; shift >= 0; shift -= 8) {
        if (t < 256) hist[t] = 0;
        __syncthreads();
        unsigned pref = s_pref;
        int kk0 = s_kk;
        for (int i = t; i < L; i += 1024) {
            unsigned v = u[i];
            bool in_set = (shift == 24) || ((v >> (shift + 8)) == pref);
            if (in_set) atomicAdd(&hist[(v >> shift) & 255], 1);
        }
        __syncthreads();
        // parallel suffix sums: ss[j] = sum_{i>=j} hist[i]
        if (t < 256) scan_s[t] = hist[t];
        __syncthreads();
        #pragma unroll
        for (int off = 1; off < 256; off <<= 1) {
            int v2 = 0;
            if (t < 256) {
                v2 = scan_s[t];
                if (t + off < 256) v2 += scan_s[t + off];
            }
            __syncthreads();
            if (t < 256) scan_s[t] = v2;
            __syncthreads();
        }
        // unique j with ss[j] >= kk > ss[j+1]
        if (t < 256) {
            int ssj  = scan_s[t];
            int ssj1 = (t < 255) ? scan_s[t + 1] : 0;
            if (ssj >= kk0 && ssj1 < kk0) {
                s_kk = kk0 - ssj1;
                s_pref = (pref << 8) | (unsigned)t;
            }
        }
        __syncthreads();
    }
    unsigned thr = s_pref;
    int need = s_kk;

    int base = t * 4;
    unsigned v0 = u[base], v1 = u[base+1], v2 = u[base+2], v3 = u[base+3];
    int eq0 = (v0 == thr), eq1 = (v1 == thr), eq2 = (v2 == thr), eq3 = (v3 == thr);
    scan_s[t] = eq0 + eq1 + eq2 + eq3;
    __syncthreads();
    for (int off = 1; off < 1024; off <<= 1) {
        int v = scan_s[t];
        if (t >= off) v += scan_s[t - off];
        __syncthreads();
        scan_s[t] = v;
        __syncthreads();
    }
    int erun = (t > 0) ? scan_s[t - 1] : 0;
    int sel[4];
    {
        int r = erun;
        sel[0] = (v0 > thr) || (eq0 && r < need); r += eq0;
        sel[1] = (v1 > thr) || (eq1 && r < need); r += eq1;
        sel[2] = (v2 > thr) || (eq2 && r < need); r += eq2;
        sel[3] = (v3 > thr) || (eq3 && r < need);
    }
    __syncthreads();

    scan_s[t] = sel[0] + sel[1] + sel[2] + sel[3];
    __syncthreads();
    for (int off = 1; off < 1024; off <<= 1) {
        int v = scan_s[t];
        if (t >= off) v += scan_s[t - off];
        __syncthreads();
        scan_s[t] = v;
        __syncthreads();
    }
    int run = (t > 0) ? scan_s[t - 1] : 0;
    #pragma unroll
    for (int j = 0; j < 4; ++j) {
        int idx = base + j;
        if (sel[j]) { sel_rows[b * K + run] = b * L + idx; run++; }
        else        { byp_rows[b * (L - K) + (idx - run)] = b * L + idx; }
    }
}

// ======== 256xBN-tile GEMM core: single-barrier window + depth-1 register
//          pipeline on fragments ========
// 8 waves (2M x 4N), per-wave 128 x BN/4 output, BK=32, 4-slot LDS ring,
// stage distance 3, counted s_waitcnt vmcnt(LW) (never 0 in steady state),
// setprio around the MFMA block. Per window t:
//   {stage slot t+3 -> read ag(t) + af/bfr(t+1) -> sched_barrier(0) ->
//    prio1: 8x NI MFMA on af/bfr(t) [in regs] + ag(t) [lands under cluster-1]
//    -> vmcnt(LW) -> s_barrier}
// Slot liveness at window t: t (ag read), t+1 (next-frag read), t+2
// (landed), t+3 (landing) -- exactly the 4-slot ring. Reads of slot t+1
// are safe: stage(t+1) retired by vmcnt(LW) at end of window t-1 (newest
// LW outstanding = stage(t+2)). Overwrite of slot s (stage at window s-3)
// is >= 2 barriers after slot s's last readers. Swizzle: 16B slot =
// quad ^ ((row>>1)&3), inverse applied to global source (linear gload_lds
// dest). Conflict-free (verified: SQ_LDS_BANK_CONFLICT=0).
template <int BN, bool GATHER_A, bool SCATTER_OUT, bool GELU_ACT, typename OT>
__device__ __forceinline__ void gemm256_core(
    const __bf16* __restrict__ A, const __bf16* __restrict__ W,
    OT* __restrict__ Out, const int* __restrict__ rows,
    int lda, int kBeg, int kLen, int ldo, int mt, int nt,
    __bf16* ringA, __bf16* ringB, int* rs)
{
    constexpr int BM = 256, BK = 32;
    constexpr int NB = BN / 128;      // B-staging calls per tile (2 or 1)
    constexpr int NI = BN / 64;       // ni per wave (4 or 2)
    constexpr int LW = 2 + NB;        // staging loads per window
    constexpr int SA = BM * BK;       // ring slot stride (elements)
    constexpr int SB = BN * BK;
    const int tid = threadIdx.x;      // 0..511
    const int m0 = mt * BM, n0 = nt * BN;

    if (tid < BM) rs[tid] = (GATHER_A || SCATTER_OUT) ? rows[m0 + tid] : 0;
    __syncthreads();

    const int srow = tid >> 2;
    const int scol = ((tid & 3) ^ ((tid >> 3) & 3)) * 8;   // elements
    const __bf16* asrc[2]; const __bf16* bsrc[NB];
    #pragma unroll
    for (int c = 0; c < 2; ++c) {
        int lr = c * 128 + srow;
        int ar = GATHER_A ? rs[lr] : (m0 + lr);
        asrc[c] = A + (size_t)ar * lda + kBeg + scol;
    }
    #pragma unroll
    for (int c = 0; c < NB; ++c)
        bsrc[c] = W + (size_t)(n0 + c * 128 + srow) * lda + kBeg + scol;
    const int ldst = tid * 8;   // element offset of this thread's 16B

    const int NT = kLen / BK;   // even (32 or 64)

    auto STAGE = [&](int t) {
        #pragma unroll
        for (int c = 0; c < 2; ++c)
            async_cp16(asrc[c] + t * BK, ringA + (t & 3) * SA + c * 4096 + ldst);
        #pragma unroll
        for (int c = 0; c < NB; ++c)
            async_cp16(bsrc[c] + t * BK, ringB + (t & 3) * SB + c * 4096 + ldst);
    };

    // prologue: stage slots 0,1,2; retire 0,1 (newest LW = slot 2 may fly)
    STAGE(0); STAGE(1); STAGE(2);
    if constexpr (BN == 256) asm volatile("s_waitcnt vmcnt(4)" ::: "memory");
    else                     asm volatile("s_waitcnt vmcnt(3)" ::: "memory");
    asm volatile("s_barrier" ::: "memory");

    f32x4 acc[8][NI] = {};
    const int lane = tid & 63;
    const int wv = tid >> 6;
    const int wr = (wv >> 2) * 128;              // wave M offset
    const int wc = (wv & 3) * (BN / 4);          // wave N offset
    const int r = lane & 15, quad = lane >> 4;
    const int rdoff = (quad ^ ((r >> 1) & 3)) * 8;   // swizzled 16B slot

    bf16x8 afE[4], bfrE[NI], afO[4], bfrO[NI], ag[4];

    auto READ_AB = [&](int t, bf16x8 (&af)[4], bf16x8 (&bfr)[NI]) {
        const __bf16* As = ringA + (t & 3) * SA;
        const __bf16* Bs = ringB + (t & 3) * SB;
        #pragma unroll
        for (int mi = 0; mi < 4; ++mi)
            af[mi] = *(const bf16x8*)(As + (wr + mi * 16 + r) * BK + rdoff);
        #pragma unroll
        for (int ni = 0; ni < NI; ++ni)
            bfr[ni] = *(const bf16x8*)(Bs + (wc + ni * 16 + r) * BK + rdoff);
    };

    READ_AB(0, afE, bfrE);      // slot 0 landed & barrier-crossed

    auto WINDOW = [&](int t, bf16x8 (&caf)[4], bf16x8 (&cbf)[NI],
                      bf16x8 (&naf)[4], bf16x8 (&nbf)[NI]) {
        const __bf16* As = ringA + (t & 3) * SA;
        const bool pf = (t + 3 < NT);
        if (pf) STAGE(t + 3);
        // upper-M frags of current slot (land under cluster-1's MFMAs)
        #pragma unroll
        for (int mi = 0; mi < 4; ++mi)
            ag[mi] = *(const bf16x8*)(As + (wr + 64 + mi * 16 + r) * BK + rdoff);
        // next window's frags into the other register set
        if (t + 1 < NT) READ_AB(t + 1, naf, nbf);
        __builtin_amdgcn_sched_barrier(0);   // keep reads above the MFMAs
        __builtin_amdgcn_s_setprio(1);
        #pragma unroll
        for (int mi = 0; mi < 4; ++mi)
            #pragma unroll
            for (int ni = 0; ni < NI; ++ni)
                acc[mi][ni] = __builtin_amdgcn_mfma_f32_16x16x32_bf16(
                    caf[mi], cbf[ni], acc[mi][ni], 0, 0, 0);
        #pragma unroll
        for (int mi = 0; mi < 4; ++mi)
            #pragma unroll
            for (int ni = 0; ni < NI; ++ni)
                acc[4 + mi][ni] = __builtin_amdgcn_mfma_f32_16x16x32_bf16(
                    ag[mi], cbf[ni], acc[4 + mi][ni], 0, 0, 0);
        __builtin_amdgcn_s_setprio(0);
        // counted: newest LW outstanding = stage(t+3); stage(t+2) retired,
        // so next window may read slot t+2 after the barrier.
        if (pf) {
            if constexpr (BN == 256) asm volatile("s_waitcnt vmcnt(4)" ::: "memory");
            else                     asm volatile("s_waitcnt vmcnt(3)" ::: "memory");
        } else {
            asm volatile("s_waitcnt vmcnt(0)" ::: "memory");
        }
        asm volatile("s_barrier" ::: "memory");
    };

    for (int t = 0; t < NT; t += 2) {
        WINDOW(t,     afE, bfrE, afO, bfrO);
        WINDOW(t + 1, afO, bfrO, afE, bfrE);
    }

    #pragma unroll
    for (int mi = 0; mi < 8; ++mi) {
        #pragma unroll
        for (int reg = 0; reg < 4; ++reg) {
            int rowl = wr + mi * 16 + quad * 4 + reg;
            int orow = SCATTER_OUT ? rs[rowl] : (m0 + rowl);
            OT* op = Out + (size_t)orow * ldo + n0;
            #pragma unroll
            for (int ni = 0; ni < NI; ++ni) {
                float v = acc[mi][ni][reg];
                if (GELU_ACT) v = gelu_fast(v);
                op[wc + ni * 16 + r] = (OT)v;
            }
        }
    }
}

// ---- dispatch 2: 768 blocks, 1/CU, per-CU schedule ~{2 ffn1 + 1 bypass}.
//   bid < 512: ffn1 256^2 (K=1024). XCD x=bid&7 owns mt 4x..4x+3; local
//              l=bid>>3: mt=4x+((l>>3)&3), nt=(l>>5)*8+(l&7) (supertiles).
//   bid >= 512: bypass 256x128 (K=1024), dispatched last (small jobs fill
//              the final scheduling round). id=bid-512: x=id&7, v=id>>3:
//              mt=4x+(v>>3), nt=v&7.
__global__ __launch_bounds__(512, 2) void gemm_mid(
    const __bf16* __restrict__ xb, const __bf16* __restrict__ w1b,
    __bf16* __restrict__ h, const __bf16* __restrict__ wbb,
    float* __restrict__ out,
    const int* __restrict__ sel_rows, const int* __restrict__ byp_rows)
{
    __shared__ __align__(16) __bf16 ringA[4][256 * 32];
    __shared__ __align__(16) __bf16 ringB[4][256 * 32];
    __shared__ int rs[256];
    int bid = blockIdx.x;
    if (bid < 512) {
        int x = bid & 7, l = bid >> 3;
        int mt = x * 4 + ((l >> 3) & 3);
        int nt = (l >> 5) * 8 + (l & 7);
        gemm256_core<256, true, false, true, __bf16>(
            xb, w1b, h, sel_rows, 1024, 0, 1024, 4096, mt, nt,
            &ringA[0][0], &ringB[0][0], rs);
    } else {
        int id = bid - 512;
        int x = id & 7, v = id >> 3;
        int mt = x * 4 + (v >> 3);
        int nt = v & 7;
        gemm256_core<128, true, true, false, float>(
            xb, wbb, out, byp_rows, 1024, 0, 1024, 1024, mt, nt,
            &ringA[0][0], &ringB[0][0], rs);
    }
}

// ---- dispatch 3: FFN2 split-K=2, 256 blocks (1/CU). XCD x owns mt 4x..4x+3.
//   l = bid>>3 (0..31): kc=l>>4, u=l&15 -> mt=4x+(u>>2), nt=u&3.
//   kc==0: out[sel] = h@w2^T over k<2048 (scatter);
//   kc==1: p1 = h@w2^T over k>=2048 (dense, into dead xb region).
__global__ __launch_bounds__(512, 2) void gemm256_ffn2(
    const __bf16* __restrict__ h, const __bf16* __restrict__ w2b,
    float* __restrict__ out, float* __restrict__ p1,
    const int* __restrict__ sel_rows)
{
    __shared__ __align__(16) __bf16 ringA[4][256 * 32];
    __shared__ __align__(16) __bf16 ringB[4][256 * 32];
    __shared__ int rs[256];
    int x = blockIdx.x & 7, l = blockIdx.x >> 3;
    int kc = l >> 4, u = l & 15;
    int mt = x * 4 + (u >> 2);
    int nt = u & 3;
    if (kc == 0)
        gemm256_core<256, false, true, false, float>(
            h, w2b, out, sel_rows, 4096, 0, 2048, 1024, mt, nt,
            &ringA[0][0], &ringB[0][0], rs);
    else
        gemm256_core<256, false, false, false, float>(
            h, w2b, p1, nullptr, 4096, 2048, 2048, 1024, mt, nt,
            &ringA[0][0], &ringB[0][0], rs);
}

// ---- dispatch 4: out[sel_rows[s]] += p1[s]  (one wave per slot) ----
__global__ __launch_bounds__(256) void reduce_add(
    const float* __restrict__ p1, float* __restrict__ out,
    const int* __restrict__ sel_rows)
{
    int wid = (blockIdx.x * 256 + threadIdx.x) >> 6;   // slot 0..8191
    int lane = threadIdx.x & 63;
    int row = sel_rows[wid];
    const float4* a = (const float4*)(p1 + (size_t)wid * 1024);
    float4* o = (float4*)(out + (size_t)row * 1024);
    #pragma unroll
    for (int i = 0; i < 4; ++i) {
        int idx = i * 64 + lane;
        float4 v = a[idx], w = o[idx];
        v.x += w.x; v.y += w.y; v.z += w.z; v.w += w.w;
        o[idx] = v;
    }
}

extern "C" void kernel_launch(void* const* d_in, const int* in_sizes, int n_in,
                              void* d_out, int out_size, void* d_ws, size_t ws_size,
                              hipStream_t stream) {
    (void)in_sizes; (void)n_in; (void)out_size; (void)ws_size;
    const float* x  = (const float*)d_in[0];
    const float* wr = (const float*)d_in[1];
    const float* wb = (const float*)d_in[2];
    const float* w1 = (const float*)d_in[3];
    const float* w2 = (const float*)d_in[4];
    float* out = (float*)d_out;

    const int B = 4, L = 4096, D = 1024, DFF = 4096, KSEL = 2048;
    const int M = B * KSEL;           // 8192
    const int NTOK = B * L;           // 16384

    size_t n_x = (size_t)NTOK * D, n_wb = (size_t)D * D;
    size_t n_w1 = (size_t)DFF * D, n_w2 = (size_t)D * DFF;

    char* ws = (char*)d_ws;
    float* scores = (float*)ws;            ws += sizeof(float) * (size_t)NTOK;
    int* sel_rows = (int*)ws;              ws += sizeof(int) * (size_t)M;
    int* byp_rows = (int*)ws;              ws += sizeof(int) * (size_t)M;
    uintptr_t up = ((uintptr_t)ws + 255) & ~(uintptr_t)255;
    __bf16* xb  = (__bf16*)up;             up += 2 * n_x;
    __bf16* wbb = (__bf16*)up;             up += 2 * n_wb;
    __bf16* w1b = (__bf16*)up;             up += 2 * n_w1;
    __bf16* w2b = (__bf16*)up;             up += 2 * n_w2;
    up = (up + 255) & ~(uintptr_t)255;
    __bf16* h   = (__bf16*)up;             // 8192 x 4096 bf16 = 64 MiB
    // split-K partial: reuse xb region (dead after gemm_mid); 8192x1024 f32
    // = 32 MiB == sizeof(xb).
    float* p1 = (float*)xb;

    int nbr = NTOK / 4;                              // 4096 router blocks
    int ncv = (int)((n_wb + n_w1 + n_w2) / 8 / 256); // 4608 cvt blocks
    prep<<<nbr + ncv, 256, 0, stream>>>(
        x, wr, scores, xb, wb, w1, w2, wbb, w1b, w2b,
        nbr, (int)(n_wb / 8), (int)(n_w1 / 8), (int)(n_w2 / 8));
    topk_build<<<B, 1024, 0, stream>>>(scores, sel_rows, byp_rows);

    // FFN1 (512 jobs, 256^2) + bypass (256 jobs, 256x128) -> ~2.5 jobs/CU
    gemm_mid<<<768, 512, 0, stream>>>(xb, w1b, h, wbb, out, sel_rows, byp_rows);
    // FFN2 split-K=2: 256 blocks, 1/CU, XCD-owned supertiles
    gemm256_ffn2<<<256, 512, 0, stream>>>(h, w2b, out, p1, sel_rows);
    // out[sel] += p1
    reduce_add<<<M / 4, 256, 0, stream>>>(p1, out, sel_rows);
}

// Round 9
// 327.396 us; speedup vs baseline: 1.1442x; 1.1442x over previous
//
#include <hip/hip_runtime.h>
#include <stdint.h>
#include <math.h>

// MixtureOfDepths: B=4, L=4096, D=1024, Dff=4096, capacity 0.5 -> k=2048.
// R13 -> R14: REVERT R13's register pipeline (137.9us, third failed schedule
// graft: R11 128^2-occupancy 149us, R12 2-phase 137.5us, R13 reg-pipe 137.9us
// -- consistent with guide m196/m141: anything between the simple
// single-barrier loop and the exact m201 8-phase template is null-negative).
// Core restored VERBATIM to the R10 single-barrier ring (measured 108.9us,
// MfmaUtil 33.8%). New win instead: FFN2 retiled from {split-K=2 + reduce_add}
// to 256 uniform 256x128 jobs at full K=4096 (same per-job FLOP, proven
// BN=128 path, 1/CU single round) -> deletes reduce_add dispatch and the
// 96MB p1 round-trip. Single fp32 MFMA chain k=0..4095 = R0's original
// order (absmax 0.03125 then too).

typedef __attribute__((ext_vector_type(8))) __bf16 bf16x8;
typedef __attribute__((ext_vector_type(4))) float f32x4;

__device__ __forceinline__ void async_cp16(const __bf16* g, __bf16* l) {
    __builtin_amdgcn_global_load_lds(
        (__attribute__((address_space(1))) void*)g,
        (__attribute__((address_space(3))) void*)l,
        16, 0, 0);
}

// gelu_tanh(x) == x * sigmoid(2*0.7978845608*(x + 0.044715 x^3)), exactly.
__device__ __forceinline__ float gelu_fast(float x) {
    float u = 1.5957691216057308f * x * (1.0f + 0.044715f * x * x);
    return x / (1.0f + __expf(-u));
}

// ---------- merged: router scores + x->bf16 (blocks < NBR) and
//            weights->bf16 (blocks >= NBR) ----------
// NOTE: score math must stay bit-identical across rounds (selection boundary).
__global__ __launch_bounds__(256) void prep(
    const float* __restrict__ x, const float* __restrict__ wr,
    float* __restrict__ scores, __bf16* __restrict__ xb,
    const float* __restrict__ p0, const float* __restrict__ p1,
    const float* __restrict__ p2,
    __bf16* __restrict__ o0, __bf16* __restrict__ o1, __bf16* __restrict__ o2,
    int nbr, int c0, int c1, int c2)
{
    if ((int)blockIdx.x < nbr) {
        int wid  = (blockIdx.x * blockDim.x + threadIdx.x) >> 6;  // token id
        int lane = threadIdx.x & 63;
        const float* row = x + (size_t)wid * 1024;
        __bf16* orow = xb + (size_t)wid * 1024;
        double s = 0.0;
        #pragma unroll
        for (int it = 0; it < 2; ++it) {
            int base = it * 512 + lane * 8;
            float4 a  = *(const float4*)(row + base);
            float4 b  = *(const float4*)(row + base + 4);
            float4 wa = *(const float4*)(wr + base);
            float4 wc = *(const float4*)(wr + base + 4);
            s += (double)a.x * wa.x + (double)a.y * wa.y
               + (double)a.z * wa.z + (double)a.w * wa.w
               + (double)b.x * wc.x + (double)b.y * wc.y
               + (double)b.z * wc.z + (double)b.w * wc.w;
            bf16x8 v;
            v[0] = (__bf16)a.x; v[1] = (__bf16)a.y; v[2] = (__bf16)a.z; v[3] = (__bf16)a.w;
            v[4] = (__bf16)b.x; v[5] = (__bf16)b.y; v[6] = (__bf16)b.z; v[7] = (__bf16)b.w;
            *(bf16x8*)(orow + base) = v;
        }
        #pragma unroll
        for (int off = 32; off > 0; off >>= 1) s += __shfl_down(s, off, 64);
        if (lane == 0) scores[wid] = (float)s;
        return;
    }
    int chunk = (blockIdx.x - nbr) * 256 + threadIdx.x;
    const float* in; __bf16* out;
    if (chunk < c0)                { in = p0 + (size_t)chunk * 8;             out = o0 + (size_t)chunk * 8; }
    else if (chunk < c0 + c1)      { int c = chunk - c0;      in = p1 + (size_t)c * 8; out = o1 + (size_t)c * 8; }
    else if (chunk < c0 + c1 + c2) { int c = chunk - c0 - c1; in = p2 + (size_t)c * 8; out = o2 + (size_t)c * 8; }
    else return;
    float4 a = *(const float4*)(in);
    float4 b = *(const float4*)(in + 4);
    bf16x8 v;
    v[0] = (__bf16)a.x; v[1] = (__bf16)a.y; v[2] = (__bf16)a.z; v[3] = (__bf16)a.w;
    v[4] = (__bf16)b.x; v[5] = (__bf16)b.y; v[6] = (__bf16)b.z; v[7] = (__bf16)b.w;
    *(bf16x8*)(out) = v;
}

// ---------------- per-batch top-k via 8-bit MSB-first radix select ----------------
// Same selected set as a full descending sort with tie-break "lower index wins".
__global__ __launch_bounds__(1024) void topk_build(
    const float* __restrict__ scores,
    int* __restrict__ sel_rows, int* __restrict__ byp_rows)
{
    const int L = 4096, K = 2048;
    __shared__ unsigned u[4096];
    __shared__ int hist[256];
    __shared__ int scan_s[1024];
    __shared__ unsigned s_pref;
    __shared__ int s_kk;
    int b = blockIdx.x, t = threadIdx.x;

    for (int i = t; i < L; i += 1024) {
        unsigned v = __float_as_uint(scores[b * L + i]);
        v = (v & 0x80000000u) ? ~v : (v | 0x80000000u);   // order-preserving map
        u[i] = v;
    }
    if (t == 0) { s_pref = 0; s_kk = K; }
    __syncthreads();

    for (int shift = 24; shift >= 0; shift -= 8) {
        if (t < 256) hist[t] = 0;
        __syncthreads();
        unsigned pref = s_pref;
        int kk0 = s_kk;
        for (int i = t; i < L; i += 1024) {
            unsigned v = u[i];
            bool in_set = (shift == 24) || ((v >> (shift + 8)) == pref);
            if (in_set) atomicAdd(&hist[(v >> shift) & 255], 1);
        }
        __syncthreads();
        // parallel suffix sums: ss[j] = sum_{i>=j} hist[i]
        if (t < 256) scan_s[t] = hist[t];
        __syncthreads();
        #pragma unroll
        for (int off = 1; off < 256; off <<= 1) {
            int v2 = 0;
            if (t < 256) {
                v2 = scan_s[t];
                if (t + off < 256) v2 += scan_s[t + off];
            }
            __syncthreads();
            if (t < 256) scan_s[t] = v2;
            __syncthreads();
        }
        // unique j with ss[j] >= kk > ss[j+1]
        if (t < 256) {
            int ssj  = scan_s[t];
            int ssj1 = (t < 255) ? scan_s[t + 1] : 0;
            if (ssj >= kk0 && ssj1 < kk0) {
                s_kk = kk0 - ssj1;
                s_pref = (pref << 8) | (unsigned)t;
            }
        }
        __syncthreads();
    }
    unsigned thr = s_pref;
    int need = s_kk;

    int base = t * 4;
    unsigned v0 = u[base], v1 = u[base+1], v2 = u[base+2], v3 = u[base+3];
    int eq0 = (v0 == thr), eq1 = (v1 == thr), eq2 = (v2 == thr), eq3 = (v3 == thr);
    scan_s[t] = eq0 + eq1 + eq2 + eq3;
    __syncthreads();
    for (int off = 1; off < 1024; off <<= 1) {
        int v = scan_s[t];
        if (t >= off) v += scan_s[t - off];
        __syncthreads();
        scan_s[t] = v;
        __syncthreads();
    }
    int erun = (t > 0) ? scan_s[t - 1] : 0;
    int sel[4];
    {
        int r = erun;
        sel[0] = (v0 > thr) || (eq0 && r < need); r += eq0;
        sel[1] = (v1 > thr) || (eq1 && r < need); r += eq1;
        sel[2] = (v2 > thr) || (eq2 && r < need); r += eq2;
        sel[3] = (v3 > thr) || (eq3 && r < need);
    }
    __syncthreads();

    scan_s[t] = sel[0] + sel[1] + sel[2] + sel[3];
    __syncthreads();
    for (int off = 1; off < 1024; off <<= 1) {
        int v = scan_s[t];
        if (t >= off) v += scan_s[t - off];
        __syncthreads();
        scan_s[t] = v;
        __syncthreads();
    }
    int run = (t > 0) ? scan_s[t - 1] : 0;
    #pragma unroll
    for (int j = 0; j < 4; ++j) {
        int idx = base + j;
        if (sel[j]) { sel_rows[b * K + run] = b * L + idx; run++; }
        else        { byp_rows[b * (L - K) + (idx - run)] = b * L + idx; }
    }
}

// ======== 256xBN-tile deep-pipelined GEMM core, single-barrier window ========
// (R10 core, verbatim -- measured 108.9us gemm_mid, MfmaUtil 33.8%.)
// 8 waves (2M x 4N), per-wave 128 x BN/4 output, BK=32, 4-slot LDS ring.
// Per window: {12|10 ds_read_b128 + staging (2+NB gload_lds) -> 32|16 MFMA
// (compiler interleaves via fine-grained lgkmcnt) -> counted vmcnt(2+NB) ->
// s_barrier}. vmcnt never 0 in steady state. Hazards: reads of slot t
// consumed (lgkmcnt) before barrier t; staging into slot (t+2)&3 occurs
// after barrier t+1 > window t-2's readers. Swizzle: 16B slot =
// quad ^ ((row>>1)&3), inverse applied to global source (linear gload_lds
// dest). Conflict-free (verified: SQ_LDS_BANK_CONFLICT=0).
template <int BN, bool GATHER_A, bool SCATTER_OUT, bool GELU_ACT, typename OT>
__device__ __forceinline__ void gemm256_core(
    const __bf16* __restrict__ A, const __bf16* __restrict__ W,
    OT* __restrict__ Out, const int* __restrict__ rows,
    int lda, int kBeg, int kLen, int ldo, int mt, int nt,
    __bf16* ringA, __bf16* ringB, int* rs)
{
    constexpr int BM = 256, BK = 32;
    constexpr int NB = BN / 128;      // B-staging calls per tile (2 or 1)
    constexpr int NI = BN / 64;       // ni per wave (4 or 2)
    constexpr int SA = BM * BK;       // ring slot stride (elements)
    constexpr int SB = BN * BK;
    const int tid = threadIdx.x;      // 0..511
    const int m0 = mt * BM, n0 = nt * BN;

    if (tid < BM) rs[tid] = (GATHER_A || SCATTER_OUT) ? rows[m0 + tid] : 0;
    __syncthreads();

    const int srow = tid >> 2;
    const int scol = ((tid & 3) ^ ((tid >> 3) & 3)) * 8;   // elements
    const __bf16* asrc[2]; const __bf16* bsrc[NB];
    #pragma unroll
    for (int c = 0; c < 2; ++c) {
        int lr = c * 128 + srow;
        int ar = GATHER_A ? rs[lr] : (m0 + lr);
        asrc[c] = A + (size_t)ar * lda + kBeg + scol;
    }
    #pragma unroll
    for (int c = 0; c < NB; ++c)
        bsrc[c] = W + (size_t)(n0 + c * 128 + srow) * lda + kBeg + scol;
    const int ldst = tid * 8;   // element offset of this thread's 16B

    const int NT = kLen / BK;
    #pragma unroll
    for (int t = 0; t < 2; ++t) {
        #pragma unroll
        for (int c = 0; c < 2; ++c)
            async_cp16(asrc[c] + t * BK, ringA + t * SA + c * 4096 + ldst);
        #pragma unroll
        for (int c = 0; c < NB; ++c)
            async_cp16(bsrc[c] + t * BK, ringB + t * SB + c * 4096 + ldst);
    }
    if constexpr (BN == 256) asm volatile("s_waitcnt vmcnt(4)" ::: "memory");
    else                     asm volatile("s_waitcnt vmcnt(3)" ::: "memory");
    asm volatile("s_barrier" ::: "memory");

    f32x4 acc[8][NI] = {};
    const int lane = tid & 63;
    const int wv = tid >> 6;
    const int wr = (wv >> 2) * 128;              // wave M offset
    const int wc = (wv & 3) * (BN / 4);          // wave N offset
    const int r = lane & 15, quad = lane >> 4;
    const int rdoff = (quad ^ ((r >> 1) & 3)) * 8;   // swizzled 16B slot

    for (int t = 0; t < NT; ++t) {
        const __bf16* As = ringA + (t & 3) * SA;
        const __bf16* Bs = ringB + (t & 3) * SB;
        const bool pf = (t + 2 < NT);

        // all fragment reads for this window, issued up front
        bf16x8 af[4], ag[4], bfr[NI];
        #pragma unroll
        for (int mi = 0; mi < 4; ++mi)
            af[mi] = *(const bf16x8*)(As + (wr + mi * 16 + r) * BK + rdoff);
        #pragma unroll
        for (int ni = 0; ni < NI; ++ni)
            bfr[ni] = *(const bf16x8*)(Bs + (wc + ni * 16 + r) * BK + rdoff);
        #pragma unroll
        for (int mi = 0; mi < 4; ++mi)
            ag[mi] = *(const bf16x8*)(As + (wr + 64 + mi * 16 + r) * BK + rdoff);
        // staging into slot t+2 (ring distance 2)
        if (pf) {
            #pragma unroll
            for (int c = 0; c < 2; ++c)
                async_cp16(asrc[c] + (t + 2) * BK,
                           ringA + ((t + 2) & 3) * SA + c * 4096 + ldst);
            #pragma unroll
            for (int c = 0; c < NB; ++c)
                async_cp16(bsrc[c] + (t + 2) * BK,
                           ringB + ((t + 2) & 3) * SB + c * 4096 + ldst);
        }
        __builtin_amdgcn_s_setprio(1);
        #pragma unroll
        for (int mi = 0; mi < 4; ++mi)
            #pragma unroll
            for (int ni = 0; ni < NI; ++ni)
                acc[mi][ni] = __builtin_amdgcn_mfma_f32_16x16x32_bf16(
                    af[mi], bfr[ni], acc[mi][ni], 0, 0, 0);
        #pragma unroll
        for (int mi = 0; mi < 4; ++mi)
            #pragma unroll
            for (int ni = 0; ni < NI; ++ni)
                acc[4 + mi][ni] = __builtin_amdgcn_mfma_f32_16x16x32_bf16(
                    ag[mi], bfr[ni], acc[4 + mi][ni], 0, 0, 0);
        __builtin_amdgcn_s_setprio(0);
        // counted wait: only this window's staging may stay in flight ->
        // slot t+1 (staged at window t-1) has fully landed.
        if (pf) {
            if constexpr (BN == 256) asm volatile("s_waitcnt vmcnt(4)" ::: "memory");
            else                     asm volatile("s_waitcnt vmcnt(3)" ::: "memory");
        } else {
            asm volatile("s_waitcnt vmcnt(0)" ::: "memory");
        }
        asm volatile("s_barrier" ::: "memory");
    }

    #pragma unroll
    for (int mi = 0; mi < 8; ++mi) {
        #pragma unroll
        for (int reg = 0; reg < 4; ++reg) {
            int rowl = wr + mi * 16 + quad * 4 + reg;
            int orow = SCATTER_OUT ? rs[rowl] : (m0 + rowl);
            OT* op = Out + (size_t)orow * ldo + n0;
            #pragma unroll
            for (int ni = 0; ni < NI; ++ni) {
                float v = acc[mi][ni][reg];
                if (GELU_ACT) v = gelu_fast(v);
                op[wc + ni * 16 + r] = (OT)v;
            }
        }
    }
}

// ---- dispatch 2: 768 blocks, 1/CU, per-CU schedule ~{2 ffn1 + 1 bypass}.
//   bid < 512: ffn1 256^2 (K=1024). XCD x=bid&7 owns mt 4x..4x+3; local
//              l=bid>>3: mt=4x+((l>>3)&3), nt=(l>>5)*8+(l&7) (supertiles).
//   bid >= 512: bypass 256x128 (K=1024), dispatched last (small jobs fill
//              the final scheduling round). id=bid-512: x=id&7, v=id>>3:
//              mt=4x+(v>>3), nt=v&7.
__global__ __launch_bounds__(512, 2) void gemm_mid(
    const __bf16* __restrict__ xb, const __bf16* __restrict__ w1b,
    __bf16* __restrict__ h, const __bf16* __restrict__ wbb,
    float* __restrict__ out,
    const int* __restrict__ sel_rows, const int* __restrict__ byp_rows)
{
    __shared__ __align__(16) __bf16 ringA[4][256 * 32];
    __shared__ __align__(16) __bf16 ringB[4][256 * 32];
    __shared__ int rs[256];
    int bid = blockIdx.x;
    if (bid < 512) {
        int x = bid & 7, l = bid >> 3;
        int mt = x * 4 + ((l >> 3) & 3);
        int nt = (l >> 5) * 8 + (l & 7);
        gemm256_core<256, true, false, true, __bf16>(
            xb, w1b, h, sel_rows, 1024, 0, 1024, 4096, mt, nt,
            &ringA[0][0], &ringB[0][0], rs);
    } else {
        int id = bid - 512;
        int x = id & 7, v = id >> 3;
        int mt = x * 4 + (v >> 3);
        int nt = v & 7;
        gemm256_core<128, true, true, false, float>(
            xb, wbb, out, byp_rows, 1024, 0, 1024, 1024, mt, nt,
            &ringA[0][0], &ringB[0][0], rs);
    }
}

// ---- dispatch 3: FFN2 as 256 uniform 256x128 jobs, FULL K=4096 (no
//      split-K, no reduce pass). 1/CU, single round. XCD x owns mt
//      4x..4x+3; l=bid>>3 (0..31): mt=4x+(l>>3), nt=l&7.
//      out[sel] = h@w2^T, scatter rows. Single fp32 MFMA accumulation
//      chain over k=0..4095 (same order as the R0 kernel; absmax 0.03125).
__global__ __launch_bounds__(512, 2) void gemm_ffn2(
    const __bf16* __restrict__ h, const __bf16* __restrict__ w2b,
    float* __restrict__ out, const int* __restrict__ sel_rows)
{
    __shared__ __align__(16) __bf16 ringA[4][256 * 32];
    __shared__ __align__(16) __bf16 ringB[4][128 * 32];
    __shared__ int rs[256];
    int x = blockIdx.x & 7, l = blockIdx.x >> 3;
    int mt = x * 4 + (l >> 3);
    int nt = l & 7;
    gemm256_core<128, false, true, false, float>(
        h, w2b, out, sel_rows, 4096, 0, 4096, 1024, mt, nt,
        &ringA[0][0], &ringB[0][0], rs);
}

extern "C" void kernel_launch(void* const* d_in, const int* in_sizes, int n_in,
                              void* d_out, int out_size, void* d_ws, size_t ws_size,
                              hipStream_t stream) {
    (void)in_sizes; (void)n_in; (void)out_size; (void)ws_size;
    const float* x  = (const float*)d_in[0];
    const float* wr = (const float*)d_in[1];
    const float* wb = (const float*)d_in[2];
    const float* w1 = (const float*)d_in[3];
    const float* w2 = (const float*)d_in[4];
    float* out = (float*)d_out;

    const int B = 4, L = 4096, D = 1024, DFF = 4096, KSEL = 2048;
    const int M = B * KSEL;           // 8192
    const int NTOK = B * L;           // 16384

    size_t n_x = (size_t)NTOK * D, n_wb = (size_t)D * D;
    size_t n_w1 = (size_t)DFF * D, n_w2 = (size_t)D * DFF;

    char* ws = (char*)d_ws;
    float* scores = (float*)ws;            ws += sizeof(float) * (size_t)NTOK;
    int* sel_rows = (int*)ws;              ws += sizeof(int) * (size_t)M;
    int* byp_rows = (int*)ws;              ws += sizeof(int) * (size_t)M;
    uintptr_t up = ((uintptr_t)ws + 255) & ~(uintptr_t)255;
    __bf16* xb  = (__bf16*)up;             up += 2 * n_x;
    __bf16* wbb = (__bf16*)up;             up += 2 * n_wb;
    __bf16* w1b = (__bf16*)up;             up += 2 * n_w1;
    __bf16* w2b = (__bf16*)up;             up += 2 * n_w2;
    up = (up + 255) & ~(uintptr_t)255;
    __bf16* h   = (__bf16*)up;             // 8192 x 4096 bf16 = 64 MiB

    int nbr = NTOK / 4;                              // 4096 router blocks
    int ncv = (int)((n_wb + n_w1 + n_w2) / 8 / 256); // 4608 cvt blocks
    prep<<<nbr + ncv, 256, 0, stream>>>(
        x, wr, scores, xb, wb, w1, w2, wbb, w1b, w2b,
        nbr, (int)(n_wb / 8), (int)(n_w1 / 8), (int)(n_w2 / 8));
    topk_build<<<B, 1024, 0, stream>>>(scores, sel_rows, byp_rows);

    // FFN1 (512 jobs, 256^2) + bypass (256 jobs, 256x128) -> ~2.5 jobs/CU
    gemm_mid<<<768, 512, 0, stream>>>(xb, w1b, h, wbb, out, sel_rows, byp_rows);
    // FFN2: 256 uniform 256x128 jobs, full K=4096, 1/CU, no reduce pass
    gemm_ffn2<<<256, 512, 0, stream>>>(h, w2b, out, sel_rows);
}